// Round 1
// baseline (1517.304 us; speedup 1.0000x reference)
//
#include <hip/hip_runtime.h>
#include <math.h>

#define DIMD 1024
#define NSTATE 64
#define INNERD 2048
#define NB 2
#define NL 1024
#define NT (NB*NL)            // 2048 tokens
#define EPSR 1.1920929e-07f

__device__ __forceinline__ float silu_f(float x)     { return x / (1.0f + __expf(-x)); }
__device__ __forceinline__ float softplus_f(float x) { return (x > 20.0f) ? x : log1pf(__expf(x)); }

// ---------------- RMSNorm: one block per row (1024 elems, 256 thr × float4) ----
__global__ __launch_bounds__(256) void rmsnorm_kernel(const float* __restrict__ x,
                                                      const float* __restrict__ w,
                                                      float* __restrict__ xn) {
    int row = blockIdx.x;
    float4 v = ((const float4*)(x + (size_t)row * DIMD))[threadIdx.x];
    float ss = v.x*v.x + v.y*v.y + v.z*v.z + v.w*v.w;
    #pragma unroll
    for (int off = 32; off > 0; off >>= 1) ss += __shfl_xor(ss, off, 64);
    __shared__ float sred[4];
    int wid = threadIdx.x >> 6;
    if ((threadIdx.x & 63) == 0) sred[wid] = ss;
    __syncthreads();
    float tot = sred[0] + sred[1] + sred[2] + sred[3];
    float scale = rsqrtf(tot * (1.0f / DIMD) + EPSR);
    float4 wv = ((const float4*)w)[threadIdx.x];
    float4 o;
    o.x = v.x * scale * wv.x;
    o.y = v.y * scale * wv.y;
    o.z = v.z * scale * wv.z;
    o.w = v.w * scale * wv.w;
    ((float4*)(xn + (size_t)row * DIMD))[threadIdx.x] = o;
}

// ---------------- Generic tiled fp32 GEMM, 128x128x16, 256 thr, 8x8 per thread -
// EPI: 0 = plain C store
//      1 = softplus(acc + bias[n])
//      2 = acc + resid[m*ldr+n]
//      3 = B is two [K,64] halves (W_B | W_C); store to C (n<64) / C2 (n>=64)
template <int EPI>
__global__ __launch_bounds__(256) void gemm_kernel(const float* __restrict__ A, int lda,
                                                   const float* __restrict__ Bm, int ldb,
                                                   const float* __restrict__ B2,
                                                   float* __restrict__ C, int ldc,
                                                   float* __restrict__ C2,
                                                   const float* __restrict__ bias,
                                                   const float* __restrict__ resid, int ldr,
                                                   int M, int N, int Kdim) {
    __shared__ float As[16][132];   // [k][m], padded
    __shared__ float Bs[16][128];   // [k][n]
    int tid = threadIdx.x;
    int tx = tid & 15, ty = tid >> 4;
    int m0 = blockIdx.y * 128, n0 = blockIdx.x * 128;

    float acc[8][8] = {};

    int am = tid >> 2;            // 0..63 (+64 on second pass)
    int ak = (tid & 3) * 4;       // k within tile
    int bk = tid >> 5;            // 0..7 (+8 on second pass)
    int bn = (tid & 31) * 4;      // n within tile

    for (int k0 = 0; k0 < Kdim; k0 += 16) {
        #pragma unroll
        for (int r = 0; r < 2; ++r) {
            int m = am + r * 64;
            float4 v = *(const float4*)(A + (size_t)(m0 + m) * lda + k0 + ak);
            As[ak + 0][m] = v.x; As[ak + 1][m] = v.y;
            As[ak + 2][m] = v.z; As[ak + 3][m] = v.w;
        }
        #pragma unroll
        for (int r = 0; r < 2; ++r) {
            int k = bk + r * 8;
            float4 v;
            if (EPI == 3) {
                const float* src = (bn < 64) ? (Bm + (size_t)(k0 + k) * NSTATE + bn)
                                             : (B2 + (size_t)(k0 + k) * NSTATE + (bn - 64));
                v = *(const float4*)src;
            } else {
                v = *(const float4*)(Bm + (size_t)(k0 + k) * ldb + n0 + bn);
            }
            *(float4*)&Bs[k][bn] = v;
        }
        __syncthreads();
        #pragma unroll
        for (int k = 0; k < 16; ++k) {
            float ar[8], br[8];
            #pragma unroll
            for (int i = 0; i < 8; ++i) ar[i] = As[k][ty * 8 + i];
            #pragma unroll
            for (int j = 0; j < 8; ++j) br[j] = Bs[k][tx * 8 + j];
            #pragma unroll
            for (int i = 0; i < 8; ++i)
                #pragma unroll
                for (int j = 0; j < 8; ++j)
                    acc[i][j] = fmaf(ar[i], br[j], acc[i][j]);
        }
        __syncthreads();
    }

    #pragma unroll
    for (int i = 0; i < 8; ++i) {
        int m = m0 + ty * 8 + i;
        #pragma unroll
        for (int j = 0; j < 8; ++j) {
            int n = n0 + tx * 8 + j;
            float v = acc[i][j];
            if (EPI == 1) v = softplus_f(v + bias[n]);
            if (EPI == 2) v = v + resid[(size_t)m * ldr + n];
            if (EPI == 3) {
                if (n < 64) C[(size_t)m * NSTATE + n] = v;
                else        C2[(size_t)m * NSTATE + (n - 64)] = v;
            } else {
                C[(size_t)m * ldc + n] = v;
            }
        }
    }
}

// ---------------- causal depthwise conv (K=4) + SiLU --------------------------
// u_raw lives in xz[:, 0:2048] (row stride 4096)
__global__ __launch_bounds__(256) void conv_silu_kernel(const float* __restrict__ xz,
                                                        const float* __restrict__ cw,
                                                        const float* __restrict__ cb,
                                                        float* __restrict__ u) {
    int c = blockIdx.x * 256 + threadIdx.x;   // 0..2047
    int t = blockIdx.y;                       // 0..2047
    int b = t >> 10, l = t & 1023;
    float4 w = *(const float4*)(cw + (size_t)c * 4);
    float acc = cb[c];
    float wk[4] = {w.x, w.y, w.z, w.w};
    #pragma unroll
    for (int k = 0; k < 4; ++k) {
        int ls = l + k - 3;
        if (ls >= 0) acc = fmaf(wk[k], xz[((size_t)(b * NL + ls)) * 4096 + c], acc);
    }
    u[(size_t)t * INNERD + c] = silu_f(acc);
}

// ---------------- selective scan: one wave per (b,d), lane = state index ------
__global__ __launch_bounds__(256) void scan_kernel(const float* __restrict__ dt,
                                                   const float* __restrict__ Bx,
                                                   const float* __restrict__ Cx,
                                                   const float* __restrict__ u,
                                                   const float* __restrict__ A_log,
                                                   const float* __restrict__ Dp,
                                                   float* __restrict__ ys /* xz base, stride 4096 */) {
    int lane = threadIdx.x & 63;
    int wid  = threadIdx.x >> 6;
    int g = blockIdx.x * 4 + wid;     // 0..4095
    int b = g >> 11;
    int d = g & 2047;
    float Al  = -__expf(A_log[(size_t)d * NSTATE + lane]);
    float Dpd = Dp[d];
    float h = 0.0f;
    const float* dtp = dt + (size_t)b * NL * INNERD + d;
    const float* up  = u  + (size_t)b * NL * INNERD + d;
    const float* bxp = Bx + (size_t)b * NL * NSTATE + lane;
    const float* cxp = Cx + (size_t)b * NL * NSTATE + lane;
    float* yp = ys + (size_t)b * NL * 4096 + d;
    for (int l = 0; l < NL; ++l) {
        float dtv = dtp[(size_t)l * INNERD];
        float uv  = up [(size_t)l * INNERD];
        float bx  = bxp[(size_t)l * NSTATE];
        float cx  = cxp[(size_t)l * NSTATE];
        float dA = __expf(dtv * Al);
        h = fmaf(dtv * uv, bx, dA * h);
        float p = h * cx;
        #pragma unroll
        for (int off = 32; off > 0; off >>= 1) p += __shfl_xor(p, off, 64);
        if (lane == 0) yp[(size_t)l * 4096] = p + Dpd * uv;
    }
}

// ---------------- gate: yg = ys * silu(z) -------------------------------------
__global__ __launch_bounds__(256) void gate_kernel(const float* __restrict__ xz,
                                                   float* __restrict__ yg) {
    int t = blockIdx.y;
    int c4 = blockIdx.x * 256 + threadIdx.x;   // 0..511
    float4 yv = *(const float4*)(xz + (size_t)t * 4096 + c4 * 4);
    float4 zv = *(const float4*)(xz + (size_t)t * 4096 + 2048 + c4 * 4);
    float4 o;
    o.x = yv.x * silu_f(zv.x);
    o.y = yv.y * silu_f(zv.y);
    o.z = yv.z * silu_f(zv.z);
    o.w = yv.w * silu_f(zv.w);
    *(float4*)(yg + (size_t)t * INNERD + c4 * 4) = o;
}

extern "C" void kernel_launch(void* const* d_in, const int* in_sizes, int n_in,
                              void* d_out, int out_size, void* d_ws, size_t ws_size,
                              hipStream_t stream) {
    const float* x      = (const float*)d_in[0];
    const float* norm_w = (const float*)d_in[1];
    const float* W_in   = (const float*)d_in[2];
    const float* conv_w = (const float*)d_in[3];
    const float* conv_b = (const float*)d_in[4];
    const float* W_dt   = (const float*)d_in[5];
    const float* b_dt   = (const float*)d_in[6];
    const float* A_log  = (const float*)d_in[7];
    const float* W_B    = (const float*)d_in[8];
    const float* W_C    = (const float*)d_in[9];
    const float* Dp     = (const float*)d_in[10];
    const float* W_out  = (const float*)d_in[11];
    float* out = (float*)d_out;

    float* ws  = (float*)d_ws;
    float* xn  = ws;                     // 2,097,152
    float* xz  = xn  + 2097152;          // 8,388,608  (ys overlays cols 0..2047 later)
    float* u   = xz  + 8388608;          // 4,194,304  (reused for yg after scan)
    float* dtb = u   + 4194304;          // 4,194,304
    float* bxb = dtb + 4194304;          // 131,072
    float* cxb = bxb + 131072;           // 131,072    -> total 76.5 MB

    // 1. RMSNorm
    rmsnorm_kernel<<<NT, 256, 0, stream>>>(x, norm_w, xn);
    // 2. xz = xn @ W_in   [2048,1024]x[1024,4096]
    gemm_kernel<0><<<dim3(32, 16), 256, 0, stream>>>(xn, DIMD, W_in, 2 * INNERD, nullptr,
                                                     xz, 2 * INNERD, nullptr, nullptr,
                                                     nullptr, 0, NT, 2 * INNERD, DIMD);
    // 3. u = silu(causal_dwconv(xz[:, :2048]))
    conv_silu_kernel<<<dim3(8, NT), 256, 0, stream>>>(xz, conv_w, conv_b, u);
    // 4. dt = softplus(u @ W_dt + b_dt)   [2048,2048]x[2048,2048]
    gemm_kernel<1><<<dim3(16, 16), 256, 0, stream>>>(u, INNERD, W_dt, INNERD, nullptr,
                                                     dtb, INNERD, nullptr, b_dt,
                                                     nullptr, 0, NT, INNERD, INNERD);
    // 5. Bx, Cx = u @ [W_B | W_C]   [2048,2048]x[2048,128]
    gemm_kernel<3><<<dim3(1, 16), 256, 0, stream>>>(u, INNERD, W_B, NSTATE, W_C,
                                                    bxb, NSTATE, cxb, nullptr,
                                                    nullptr, 0, NT, 128, INNERD);
    // 6. selective scan -> ys (overlays xz cols 0..2047)
    scan_kernel<<<1024, 256, 0, stream>>>(dtb, bxb, cxb, u, A_log, Dp, xz);
    // 7. yg = ys * silu(z)   -> reuse u buffer
    gate_kernel<<<dim3(2, NT), 256, 0, stream>>>(xz, u);
    // 8. out = yg @ W_out + x   [2048,2048]x[2048,1024]
    gemm_kernel<2><<<dim3(8, 16), 256, 0, stream>>>(u, INNERD, W_out, DIMD, nullptr,
                                                    out, DIMD, nullptr, nullptr,
                                                    x, DIMD, NT, DIMD, INNERD);
}

// Round 2
// 1181.761 us; speedup vs baseline: 1.2839x; 1.2839x over previous
//
#include <hip/hip_runtime.h>
#include <math.h>

#define DIMD 1024
#define NSTATE 64
#define INNERD 2048
#define NB 2
#define NL 1024
#define NT (NB*NL)            // 2048 tokens
#define EPSR 1.1920929e-07f

__device__ __forceinline__ float silu_f(float x)     { return x / (1.0f + __expf(-x)); }
__device__ __forceinline__ float softplus_f(float x) { return (x > 20.0f) ? x : log1pf(__expf(x)); }

// ---------------- RMSNorm: one block per row (1024 elems, 256 thr × float4) ----
__global__ __launch_bounds__(256) void rmsnorm_kernel(const float* __restrict__ x,
                                                      const float* __restrict__ w,
                                                      float* __restrict__ xn) {
    int row = blockIdx.x;
    float4 v = ((const float4*)(x + (size_t)row * DIMD))[threadIdx.x];
    float ss = v.x*v.x + v.y*v.y + v.z*v.z + v.w*v.w;
    #pragma unroll
    for (int off = 32; off > 0; off >>= 1) ss += __shfl_xor(ss, off, 64);
    __shared__ float sred[4];
    int wid = threadIdx.x >> 6;
    if ((threadIdx.x & 63) == 0) sred[wid] = ss;
    __syncthreads();
    float tot = sred[0] + sred[1] + sred[2] + sred[3];
    float scale = rsqrtf(tot * (1.0f / DIMD) + EPSR);
    float4 wv = ((const float4*)w)[threadIdx.x];
    float4 o;
    o.x = v.x * scale * wv.x;
    o.y = v.y * scale * wv.y;
    o.z = v.z * scale * wv.z;
    o.w = v.w * scale * wv.w;
    ((float4*)(xn + (size_t)row * DIMD))[threadIdx.x] = o;
}

// ---------------- Generic tiled fp32 GEMM, 128x128x16, 256 thr, 8x8 per thread -
// EPI: 0 = plain C store
//      2 = acc + resid[m*ldr+n]
//      4 = fused dt|B|C: cols [0,2048) -> softplus(acc+bias[n]) into C;
//          cols [2048,2112) -> Cb; cols [2112,2176) -> Cc
template <int EPI>
__global__ __launch_bounds__(256) void gemm_kernel(const float* __restrict__ A, int lda,
                                                   const float* __restrict__ Bm, int ldb,
                                                   const float* __restrict__ Bb,
                                                   const float* __restrict__ Bc,
                                                   float* __restrict__ C, int ldc,
                                                   float* __restrict__ Cb,
                                                   float* __restrict__ Cc,
                                                   const float* __restrict__ bias,
                                                   const float* __restrict__ resid, int ldr,
                                                   int M, int N, int Kdim) {
    __shared__ float As[16][132];   // [k][m], padded
    __shared__ float Bs[16][128];   // [k][n]
    int tid = threadIdx.x;
    int tx = tid & 15, ty = tid >> 4;
    int m0 = blockIdx.y * 128, n0 = blockIdx.x * 128;

    float acc[8][8] = {};

    int am = tid >> 2;            // 0..63 (+64 on second pass)
    int ak = (tid & 3) * 4;       // k within tile
    int bk = tid >> 5;            // 0..7 (+8 on second pass)
    int bn = (tid & 31) * 4;      // n within tile

    for (int k0 = 0; k0 < Kdim; k0 += 16) {
        #pragma unroll
        for (int r = 0; r < 2; ++r) {
            int m = am + r * 64;
            float4 v = *(const float4*)(A + (size_t)(m0 + m) * lda + k0 + ak);
            As[ak + 0][m] = v.x; As[ak + 1][m] = v.y;
            As[ak + 2][m] = v.z; As[ak + 3][m] = v.w;
        }
        #pragma unroll
        for (int r = 0; r < 2; ++r) {
            int k = bk + r * 8;
            float4 v;
            if (EPI == 4) {
                int gcol = n0 + bn;
                const float* src;
                if (gcol < 2048)            src = Bm + (size_t)(k0 + k) * 2048 + gcol;
                else if (gcol < 2048 + 64)  src = Bb + (size_t)(k0 + k) * NSTATE + (gcol - 2048);
                else                        src = Bc + (size_t)(k0 + k) * NSTATE + (gcol - 2112);
                v = *(const float4*)src;
            } else {
                v = *(const float4*)(Bm + (size_t)(k0 + k) * ldb + n0 + bn);
            }
            *(float4*)&Bs[k][bn] = v;
        }
        __syncthreads();
        #pragma unroll
        for (int k = 0; k < 16; ++k) {
            float ar[8], br[8];
            #pragma unroll
            for (int i = 0; i < 8; ++i) ar[i] = As[k][ty * 8 + i];
            #pragma unroll
            for (int j = 0; j < 8; ++j) br[j] = Bs[k][tx * 8 + j];
            #pragma unroll
            for (int i = 0; i < 8; ++i)
                #pragma unroll
                for (int j = 0; j < 8; ++j)
                    acc[i][j] = fmaf(ar[i], br[j], acc[i][j]);
        }
        __syncthreads();
    }

    #pragma unroll
    for (int i = 0; i < 8; ++i) {
        int m = m0 + ty * 8 + i;
        #pragma unroll
        for (int j = 0; j < 8; ++j) {
            int n = n0 + tx * 8 + j;
            float v = acc[i][j];
            if (EPI == 4) {
                if (n < 2048)           C [(size_t)m * ldc + n] = softplus_f(v + bias[n]);
                else if (n < 2048 + 64) Cb[(size_t)m * NSTATE + (n - 2048)] = v;
                else                    Cc[(size_t)m * NSTATE + (n - 2112)] = v;
            } else if (EPI == 2) {
                C[(size_t)m * ldc + n] = v + resid[(size_t)m * ldr + n];
            } else {
                C[(size_t)m * ldc + n] = v;
            }
        }
    }
}

// ---------------- causal depthwise conv (K=4) + SiLU --------------------------
// u_raw lives in xz[:, 0:2048] (row stride 4096)
__global__ __launch_bounds__(256) void conv_silu_kernel(const float* __restrict__ xz,
                                                        const float* __restrict__ cw,
                                                        const float* __restrict__ cb,
                                                        float* __restrict__ u) {
    int c = blockIdx.x * 256 + threadIdx.x;   // 0..2047
    int t = blockIdx.y;                       // 0..2047
    int b = t >> 10, l = t & 1023;
    float4 w = *(const float4*)(cw + (size_t)c * 4);
    float acc = cb[c];
    float wk[4] = {w.x, w.y, w.z, w.w};
    #pragma unroll
    for (int k = 0; k < 4; ++k) {
        int ls = l + k - 3;
        if (ls >= 0) acc = fmaf(wk[k], xz[((size_t)(b * NL + ls)) * 4096 + c], acc);
    }
    u[(size_t)t * INNERD + c] = silu_f(acc);
}

// ---------------- selective scan: one wave per (b,d), lane = state index ------
// T=8 step batching: loads hoisted (pipelined), exp->fma chain only on critical
// path, 8 butterfly reductions interleaved stage-by-stage, batched stores.
__global__ __launch_bounds__(256) void scan_kernel(const float* __restrict__ dt,
                                                   const float* __restrict__ Bx,
                                                   const float* __restrict__ Cx,
                                                   const float* __restrict__ u,
                                                   const float* __restrict__ A_log,
                                                   const float* __restrict__ Dp,
                                                   float* __restrict__ ys /* xz base, stride 4096 */) {
    int lane = threadIdx.x & 63;
    int wid  = threadIdx.x >> 6;
    int g = blockIdx.x * 4 + wid;     // 0..4095
    int b = g >> 11;
    int d = g & 2047;
    float Al  = -__expf(A_log[(size_t)d * NSTATE + lane]);
    float Dpd = Dp[d];
    float h = 0.0f;
    const float* dtp = dt + (size_t)b * NL * INNERD + d;
    const float* up  = u  + (size_t)b * NL * INNERD + d;
    const float* bxp = Bx + (size_t)b * NL * NSTATE + lane;
    const float* cxp = Cx + (size_t)b * NL * NSTATE + lane;
    float* yp = ys + (size_t)b * NL * 4096 + d;

    for (int l0 = 0; l0 < NL; l0 += 8) {
        float dtv[8], uv[8], bx[8], cx[8];
        #pragma unroll
        for (int t = 0; t < 8; ++t) {
            dtv[t] = dtp[(size_t)(l0 + t) * INNERD];
            uv[t]  = up [(size_t)(l0 + t) * INNERD];
            bx[t]  = bxp[(size_t)(l0 + t) * NSTATE];
            cx[t]  = cxp[(size_t)(l0 + t) * NSTATE];
        }
        float p[8];
        #pragma unroll
        for (int t = 0; t < 8; ++t) {
            float dA = __expf(dtv[t] * Al);
            h = fmaf(dtv[t] * uv[t], bx[t], dA * h);
            p[t] = h * cx[t];
        }
        #pragma unroll
        for (int off = 32; off > 0; off >>= 1) {
            #pragma unroll
            for (int t = 0; t < 8; ++t) p[t] += __shfl_xor(p[t], off, 64);
        }
        if (lane == 0) {
            #pragma unroll
            for (int t = 0; t < 8; ++t)
                yp[(size_t)(l0 + t) * 4096] = p[t] + Dpd * uv[t];
        }
    }
}

// ---------------- gate: yg = ys * silu(z) -------------------------------------
__global__ __launch_bounds__(256) void gate_kernel(const float* __restrict__ xz,
                                                   float* __restrict__ yg) {
    int t = blockIdx.y;
    int c4 = blockIdx.x * 256 + threadIdx.x;   // 0..511
    float4 yv = *(const float4*)(xz + (size_t)t * 4096 + c4 * 4);
    float4 zv = *(const float4*)(xz + (size_t)t * 4096 + 2048 + c4 * 4);
    float4 o;
    o.x = yv.x * silu_f(zv.x);
    o.y = yv.y * silu_f(zv.y);
    o.z = yv.z * silu_f(zv.z);
    o.w = yv.w * silu_f(zv.w);
    *(float4*)(yg + (size_t)t * INNERD + c4 * 4) = o;
}

extern "C" void kernel_launch(void* const* d_in, const int* in_sizes, int n_in,
                              void* d_out, int out_size, void* d_ws, size_t ws_size,
                              hipStream_t stream) {
    const float* x      = (const float*)d_in[0];
    const float* norm_w = (const float*)d_in[1];
    const float* W_in   = (const float*)d_in[2];
    const float* conv_w = (const float*)d_in[3];
    const float* conv_b = (const float*)d_in[4];
    const float* W_dt   = (const float*)d_in[5];
    const float* b_dt   = (const float*)d_in[6];
    const float* A_log  = (const float*)d_in[7];
    const float* W_B    = (const float*)d_in[8];
    const float* W_C    = (const float*)d_in[9];
    const float* Dp     = (const float*)d_in[10];
    const float* W_out  = (const float*)d_in[11];
    float* out = (float*)d_out;

    float* ws  = (float*)d_ws;
    float* xn  = ws;                     // 2,097,152
    float* xz  = xn  + 2097152;          // 8,388,608  (ys overlays cols 0..2047 later)
    float* u   = xz  + 8388608;          // 4,194,304  (reused for yg after scan)
    float* dtb = u   + 4194304;          // 4,194,304
    float* bxb = dtb + 4194304;          // 131,072
    float* cxb = bxb + 131072;           // 131,072    -> total 76.5 MB

    // 1. RMSNorm
    rmsnorm_kernel<<<NT, 256, 0, stream>>>(x, norm_w, xn);
    // 2. xz = xn @ W_in   [2048,1024]x[1024,4096]
    gemm_kernel<0><<<dim3(32, 16), 256, 0, stream>>>(xn, DIMD, W_in, 2 * INNERD, nullptr, nullptr,
                                                     xz, 2 * INNERD, nullptr, nullptr, nullptr,
                                                     nullptr, 0, NT, 2 * INNERD, DIMD);
    // 3. u = silu(causal_dwconv(xz[:, :2048]))
    conv_silu_kernel<<<dim3(8, NT), 256, 0, stream>>>(xz, conv_w, conv_b, u);
    // 4+5 fused. dt = softplus(u @ W_dt + b_dt); Bx,Cx = u @ [W_B|W_C]
    //     [2048,2048]x[2048,2176]
    gemm_kernel<4><<<dim3(17, 16), 256, 0, stream>>>(u, INNERD, W_dt, INNERD, W_B, W_C,
                                                     dtb, INNERD, bxb, cxb, b_dt,
                                                     nullptr, 0, NT, 2176, INNERD);
    // 6. selective scan -> ys (overlays xz cols 0..2047)
    scan_kernel<<<1024, 256, 0, stream>>>(dtb, bxb, cxb, u, A_log, Dp, xz);
    // 7. yg = ys * silu(z)   -> reuse u buffer
    gate_kernel<<<dim3(2, NT), 256, 0, stream>>>(xz, u);
    // 8. out = yg @ W_out + x   [2048,2048]x[2048,1024]
    gemm_kernel<2><<<dim3(8, 16), 256, 0, stream>>>(u, INNERD, W_out, DIMD, nullptr, nullptr,
                                                    out, DIMD, nullptr, nullptr, nullptr,
                                                    x, DIMD, NT, DIMD, INNERD);
}

// Round 4
// 494.666 us; speedup vs baseline: 3.0673x; 2.3890x over previous
//
#include <hip/hip_runtime.h>
#include <math.h>

#define DIMD 1024
#define NSTATE 64
#define INNERD 2048
#define NB 2
#define NL 1024
#define NT (NB*NL)            // 2048 tokens
#define EPSR 1.1920929e-07f

typedef __attribute__((ext_vector_type(8))) short bf16x8;
typedef __attribute__((ext_vector_type(4))) float f32x4;
typedef unsigned short ushort_t;

__device__ __forceinline__ float silu_f(float x)     { return x / (1.0f + __expf(-x)); }
__device__ __forceinline__ float softplus_f(float x) { return (x > 20.0f) ? x : log1pf(__expf(x)); }

__device__ __forceinline__ float bf2f(ushort_t h) {
    union { unsigned u; float f; } c; c.u = ((unsigned)h) << 16; return c.f;
}
__device__ __forceinline__ ushort_t f2bf(float f) {
    union { float f; unsigned u; } c; c.f = f;
    unsigned r = c.u + 0x7FFF + ((c.u >> 16) & 1);   // RNE
    return (ushort_t)(r >> 16);
}

// ---------------- weight convert+transpose: W[K][N] f32 -> WT[row_off+n][k] bf16
// grid: (N/64, K/64), block 256
__global__ __launch_bounds__(256) void transpose_bf16_kernel(const float* __restrict__ W, int N,
                                                             ushort_t* __restrict__ WT, int ldt,
                                                             int row_off) {
    __shared__ float tile[64][65];
    int t = threadIdx.x;
    int k0 = blockIdx.y * 64, n0 = blockIdx.x * 64;
    #pragma unroll
    for (int rr = 0; rr < 4; ++rr) {
        int row = rr * 16 + (t >> 4);
        int col = (t & 15) * 4;
        float4 v = *(const float4*)(W + (size_t)(k0 + row) * N + n0 + col);
        tile[row][col + 0] = v.x; tile[row][col + 1] = v.y;
        tile[row][col + 2] = v.z; tile[row][col + 3] = v.w;
    }
    __syncthreads();
    int n = t >> 2;
    int kg = (t & 3) * 16;
    #pragma unroll
    for (int g = 0; g < 4; ++g) {
        int k = kg + g * 4;
        ushort4 o;
        o.x = f2bf(tile[k + 0][n]); o.y = f2bf(tile[k + 1][n]);
        o.z = f2bf(tile[k + 2][n]); o.w = f2bf(tile[k + 3][n]);
        *(ushort4*)(WT + (size_t)(row_off + n0 + n) * ldt + k0 + k) = o;
    }
}

// ---------------- RMSNorm -> bf16 xn ------------------------------------------
__global__ __launch_bounds__(256) void rmsnorm_kernel(const float* __restrict__ x,
                                                      const float* __restrict__ w,
                                                      ushort_t* __restrict__ xnb) {
    int row = blockIdx.x;
    float4 v = ((const float4*)(x + (size_t)row * DIMD))[threadIdx.x];
    float ss = v.x*v.x + v.y*v.y + v.z*v.z + v.w*v.w;
    #pragma unroll
    for (int off = 32; off > 0; off >>= 1) ss += __shfl_xor(ss, off, 64);
    __shared__ float sred[4];
    int wid = threadIdx.x >> 6;
    if ((threadIdx.x & 63) == 0) sred[wid] = ss;
    __syncthreads();
    float tot = sred[0] + sred[1] + sred[2] + sred[3];
    float scale = rsqrtf(tot * (1.0f / DIMD) + EPSR);
    float4 wv = ((const float4*)w)[threadIdx.x];
    ushort4 o;
    o.x = f2bf(v.x * scale * wv.x);
    o.y = f2bf(v.y * scale * wv.y);
    o.z = f2bf(v.z * scale * wv.z);
    o.w = f2bf(v.w * scale * wv.w);
    ((ushort4*)(xnb + (size_t)row * DIMD))[threadIdx.x] = o;
}

// ---------------- bf16 MFMA GEMM: C[M,N] = A[M,K] @ BT[N,K]^T ------------------
// 128x128 tile, BK=64, 4 waves 2x2, 4x4 16x16x32 frags/wave.
// EPI: 0 = plain fp32 C
//      2 = fp32 C = acc + resid
//      4 = fused dt|B|C: n<2048 -> bf16 softplus(acc+bias[n]); n in [2048,2112)
//          -> Bxo bf16; n in [2112,2176) -> Cxo bf16
template <int EPI>
__global__ __launch_bounds__(256) void mfma_gemm(const ushort_t* __restrict__ A, int lda,
                                                 const ushort_t* __restrict__ BT, int ldb,
                                                 float* __restrict__ C, int ldc,
                                                 ushort_t* __restrict__ Cb16, int ldcb,
                                                 ushort_t* __restrict__ Bxo,
                                                 ushort_t* __restrict__ Cxo,
                                                 const float* __restrict__ bias,
                                                 const float* __restrict__ resid, int ldr,
                                                 int Kdim) {
    __shared__ ushort_t As[128][72];   // +8 pad: row stride 36 dwords -> 2-way (free)
    __shared__ ushort_t Bs[128][72];
    int tid = threadIdx.x;
    int lane = tid & 63, wid = tid >> 6;
    int wr = wid >> 1, wc = wid & 1;
    int m0 = blockIdx.y * 128, n0 = blockIdx.x * 128;

    f32x4 acc[4][4] = {};

    int srow = tid >> 3;              // 0..31 (+32/r)
    int scol = (tid & 7) * 8;         // 0..56

    for (int k0 = 0; k0 < Kdim; k0 += 64) {
        #pragma unroll
        for (int r = 0; r < 4; ++r) {
            int row = r * 32 + srow;
            *(bf16x8*)&As[row][scol] = *(const bf16x8*)(A  + (size_t)(m0 + row) * lda + k0 + scol);
            *(bf16x8*)&Bs[row][scol] = *(const bf16x8*)(BT + (size_t)(n0 + row) * ldb + k0 + scol);
        }
        __syncthreads();
        #pragma unroll
        for (int kk = 0; kk < 64; kk += 32) {
            bf16x8 af[4], bfr[4];
            int fr = lane & 15;
            int fk = kk + (lane >> 4) * 8;
            #pragma unroll
            for (int mi = 0; mi < 4; ++mi)
                af[mi] = *(const bf16x8*)&As[wr * 64 + mi * 16 + fr][fk];
            #pragma unroll
            for (int ni = 0; ni < 4; ++ni)
                bfr[ni] = *(const bf16x8*)&Bs[wc * 64 + ni * 16 + fr][fk];
            #pragma unroll
            for (int mi = 0; mi < 4; ++mi)
                #pragma unroll
                for (int ni = 0; ni < 4; ++ni)
                    acc[mi][ni] = __builtin_amdgcn_mfma_f32_16x16x32_bf16(af[mi], bfr[ni], acc[mi][ni], 0, 0, 0);
        }
        __syncthreads();
    }

    #pragma unroll
    for (int mi = 0; mi < 4; ++mi) {
        int gm = m0 + wr * 64 + mi * 16 + (lane >> 4) * 4;
        #pragma unroll
        for (int ni = 0; ni < 4; ++ni) {
            int gn = n0 + wc * 64 + ni * 16 + (lane & 15);
            f32x4 v = acc[mi][ni];
            #pragma unroll
            for (int r = 0; r < 4; ++r) {
                int m = gm + r;
                float val = v[r];
                if (EPI == 0) {
                    C[(size_t)m * ldc + gn] = val;
                } else if (EPI == 2) {
                    C[(size_t)m * ldc + gn] = val + resid[(size_t)m * ldr + gn];
                } else { // EPI == 4
                    if (gn < 2048)      Cb16[(size_t)m * ldcb + gn] = f2bf(softplus_f(val + bias[gn]));
                    else if (gn < 2112) Bxo[(size_t)m * NSTATE + (gn - 2048)] = f2bf(val);
                    else                Cxo[(size_t)m * NSTATE + (gn - 2112)] = f2bf(val);
                }
            }
        }
    }
}

// ---------------- causal depthwise conv (K=4) + SiLU -> bf16 u ----------------
__global__ __launch_bounds__(256) void conv_silu_kernel(const float* __restrict__ xz,
                                                        const float* __restrict__ cw,
                                                        const float* __restrict__ cb,
                                                        ushort_t* __restrict__ ub) {
    int c = blockIdx.x * 256 + threadIdx.x;   // 0..2047
    int t = blockIdx.y;                       // 0..2047
    int b = t >> 10, l = t & 1023;
    float4 w = *(const float4*)(cw + (size_t)c * 4);
    float acc = cb[c];
    float wk[4] = {w.x, w.y, w.z, w.w};
    #pragma unroll
    for (int k = 0; k < 4; ++k) {
        int ls = l + k - 3;
        if (ls >= 0) acc = fmaf(wk[k], xz[((size_t)(b * NL + ls)) * 4096 + c], acc);
    }
    ub[(size_t)t * INNERD + c] = f2bf(silu_f(acc));
}

// ---------------- selective scan (bf16 inputs): one wave per (b,d) ------------
__global__ __launch_bounds__(256) void scan_kernel(const ushort_t* __restrict__ dt,
                                                   const ushort_t* __restrict__ Bx,
                                                   const ushort_t* __restrict__ Cx,
                                                   const ushort_t* __restrict__ u,
                                                   const float* __restrict__ A_log,
                                                   const float* __restrict__ Dp,
                                                   float* __restrict__ ys /* xz base, stride 4096 */) {
    int lane = threadIdx.x & 63;
    int wid  = threadIdx.x >> 6;
    int g = blockIdx.x * 4 + wid;     // 0..4095
    int b = g >> 11;
    int d = g & 2047;
    float Al  = -__expf(A_log[(size_t)d * NSTATE + lane]);
    float Dpd = Dp[d];
    float h = 0.0f;
    const ushort_t* dtp = dt + (size_t)b * NL * INNERD + d;
    const ushort_t* up  = u  + (size_t)b * NL * INNERD + d;
    const ushort_t* bxp = Bx + (size_t)b * NL * NSTATE + lane;
    const ushort_t* cxp = Cx + (size_t)b * NL * NSTATE + lane;
    float* yp = ys + (size_t)b * NL * 4096 + d;

    for (int l0 = 0; l0 < NL; l0 += 8) {
        float dtv[8], uv[8], bx[8], cx[8];
        #pragma unroll
        for (int t = 0; t < 8; ++t) {
            dtv[t] = bf2f(dtp[(size_t)(l0 + t) * INNERD]);
            uv[t]  = bf2f(up [(size_t)(l0 + t) * INNERD]);
            bx[t]  = bf2f(bxp[(size_t)(l0 + t) * NSTATE]);
            cx[t]  = bf2f(cxp[(size_t)(l0 + t) * NSTATE]);
        }
        float p[8];
        #pragma unroll
        for (int t = 0; t < 8; ++t) {
            float dA = __expf(dtv[t] * Al);
            h = fmaf(dtv[t] * uv[t], bx[t], dA * h);
            p[t] = h * cx[t];
        }
        #pragma unroll
        for (int off = 32; off > 0; off >>= 1) {
            #pragma unroll
            for (int t = 0; t < 8; ++t) p[t] += __shfl_xor(p[t], off, 64);
        }
        if (lane == 0) {
            #pragma unroll
            for (int t = 0; t < 8; ++t)
                yp[(size_t)(l0 + t) * 4096] = p[t] + Dpd * uv[t];
        }
    }
}

// ---------------- gate: yg = ys * silu(z) -> bf16 -----------------------------
__global__ __launch_bounds__(256) void gate_kernel(const float* __restrict__ xz,
                                                   ushort_t* __restrict__ ygb) {
    int t = blockIdx.y;
    int c4 = blockIdx.x * 256 + threadIdx.x;   // 0..511
    float4 yv = *(const float4*)(xz + (size_t)t * 4096 + c4 * 4);
    float4 zv = *(const float4*)(xz + (size_t)t * 4096 + 2048 + c4 * 4);
    ushort4 o;
    o.x = f2bf(yv.x * silu_f(zv.x));
    o.y = f2bf(yv.y * silu_f(zv.y));
    o.z = f2bf(yv.z * silu_f(zv.z));
    o.w = f2bf(yv.w * silu_f(zv.w));
    *(ushort4*)(ygb + (size_t)t * INNERD + c4 * 4) = o;
}

extern "C" void kernel_launch(void* const* d_in, const int* in_sizes, int n_in,
                              void* d_out, int out_size, void* d_ws, size_t ws_size,
                              hipStream_t stream) {
    const float* x      = (const float*)d_in[0];
    const float* norm_w = (const float*)d_in[1];
    const float* W_in   = (const float*)d_in[2];
    const float* conv_w = (const float*)d_in[3];
    const float* conv_b = (const float*)d_in[4];
    const float* W_dt   = (const float*)d_in[5];
    const float* b_dt   = (const float*)d_in[6];
    const float* A_log  = (const float*)d_in[7];
    const float* W_B    = (const float*)d_in[8];
    const float* W_C    = (const float*)d_in[9];
    const float* Dp     = (const float*)d_in[10];
    const float* W_out  = (const float*)d_in[11];
    float* out = (float*)d_out;

    // ws layout (74.5 MB total)
    float*    xz     = (float*)d_ws;                 // 8,388,608 f  (ys overlays cols 0..2047)
    ushort_t* xnb    = (ushort_t*)(xz + 8388608);    // 2,097,152
    ushort_t* ubf    = xnb    + 2097152;             // 4,194,304  (yg overwrites after scan)
    ushort_t* dtb    = ubf    + 4194304;             // 4,194,304
    ushort_t* bxb    = dtb    + 4194304;             //   131,072
    ushort_t* cxb    = bxb    + 131072;              //   131,072
    ushort_t* BTin   = cxb    + 131072;              // 4,194,304  [4096][1024]
    ushort_t* BTdtbc = BTin   + 4194304;             // 4,456,448  [2176][2048]
    ushort_t* BTout  = BTdtbc + 4456448;             // 2,097,152  [1024][2048]

    // 0. weight convert+transpose to bf16 [N][K]
    transpose_bf16_kernel<<<dim3(64, 16), 256, 0, stream>>>(W_in,  4096, BTin,   1024, 0);
    transpose_bf16_kernel<<<dim3(32, 32), 256, 0, stream>>>(W_dt,  2048, BTdtbc, 2048, 0);
    transpose_bf16_kernel<<<dim3(1,  32), 256, 0, stream>>>(W_B,     64, BTdtbc, 2048, 2048);
    transpose_bf16_kernel<<<dim3(1,  32), 256, 0, stream>>>(W_C,     64, BTdtbc, 2048, 2112);
    transpose_bf16_kernel<<<dim3(16, 32), 256, 0, stream>>>(W_out, 1024, BTout,  2048, 0);

    // 1. RMSNorm -> bf16
    rmsnorm_kernel<<<NT, 256, 0, stream>>>(x, norm_w, xnb);
    // 2. xz = xn @ W_in   [2048,1024]x[1024,4096] -> fp32
    mfma_gemm<0><<<dim3(32, 16), 256, 0, stream>>>(xnb, DIMD, BTin, DIMD,
                                                   xz, 4096, nullptr, 0, nullptr, nullptr,
                                                   nullptr, nullptr, 0, DIMD);
    // 3. u = silu(causal_dwconv(xz[:, :2048])) -> bf16
    conv_silu_kernel<<<dim3(8, NT), 256, 0, stream>>>(xz, conv_w, conv_b, ubf);
    // 4+5. dt = softplus(u@W_dt + b_dt); Bx,Cx = u@[W_B|W_C]  [2048,2048]x[2048,2176]
    mfma_gemm<4><<<dim3(17, 16), 256, 0, stream>>>(ubf, INNERD, BTdtbc, INNERD,
                                                   nullptr, 0, dtb, INNERD, bxb, cxb,
                                                   b_dt, nullptr, 0, INNERD);
    // 6. selective scan -> ys (overlays xz cols 0..2047)
    scan_kernel<<<1024, 256, 0, stream>>>(dtb, bxb, cxb, ubf, A_log, Dp, xz);
    // 7. yg = ys * silu(z) -> bf16 (reuse ubf)
    gate_kernel<<<dim3(2, NT), 256, 0, stream>>>(xz, ubf);
    // 8. out = yg @ W_out + x   [2048,2048]x[2048,1024] -> fp32
    mfma_gemm<2><<<dim3(8, 16), 256, 0, stream>>>(ubf, INNERD, BTout, INNERD,
                                                  out, DIMD, nullptr, 0, nullptr, nullptr,
                                                  nullptr, x, DIMD, INNERD);
}

// Round 6
// 346.071 us; speedup vs baseline: 4.3844x; 1.4294x over previous
//
#include <hip/hip_runtime.h>
#include <math.h>

#define DIMD 1024
#define NSTATE 64
#define INNERD 2048
#define NB 2
#define NL 1024
#define NT (NB*NL)            // 2048 tokens
#define EPSR 1.1920929e-07f

typedef __attribute__((ext_vector_type(8))) short bf16x8;
typedef __attribute__((ext_vector_type(4))) float f32x4;
typedef unsigned short ushort_t;

__device__ __forceinline__ float silu_f(float x)     { return x / (1.0f + __expf(-x)); }
__device__ __forceinline__ float softplus_f(float x) { return (x > 20.0f) ? x : log1pf(__expf(x)); }

__device__ __forceinline__ float bf2f(ushort_t h) {
    union { unsigned u; float f; } c; c.u = ((unsigned)h) << 16; return c.f;
}
__device__ __forceinline__ ushort_t f2bf(float f) {
    union { float f; unsigned u; } c; c.f = f;
    unsigned r = c.u + 0x7FFF + ((c.u >> 16) & 1);   // RNE
    return (ushort_t)(r >> 16);
}

// fold two per-lane reduction values into one (pairs exchanged across xor-mask m)
__device__ __forceinline__ float foldpair(float a, float b, int m, int lane) {
    float send = (lane & m) ? a : b;
    float recv = __shfl_xor(send, m, 64);
    float keep = (lane & m) ? b : a;
    return keep + recv;
}

// ---------------- weight convert+transpose: W[K][N] f32 -> WT[row_off+n][k] bf16
__global__ __launch_bounds__(256) void transpose_bf16_kernel(const float* __restrict__ W, int N,
                                                             ushort_t* __restrict__ WT, int ldt,
                                                             int row_off) {
    __shared__ float tile[64][65];
    int t = threadIdx.x;
    int k0 = blockIdx.y * 64, n0 = blockIdx.x * 64;
    #pragma unroll
    for (int rr = 0; rr < 4; ++rr) {
        int row = rr * 16 + (t >> 4);
        int col = (t & 15) * 4;
        float4 v = *(const float4*)(W + (size_t)(k0 + row) * N + n0 + col);
        tile[row][col + 0] = v.x; tile[row][col + 1] = v.y;
        tile[row][col + 2] = v.z; tile[row][col + 3] = v.w;
    }
    __syncthreads();
    int n = t >> 2;
    int kg = (t & 3) * 16;
    #pragma unroll
    for (int g = 0; g < 4; ++g) {
        int k = kg + g * 4;
        ushort4 o;
        o.x = f2bf(tile[k + 0][n]); o.y = f2bf(tile[k + 1][n]);
        o.z = f2bf(tile[k + 2][n]); o.w = f2bf(tile[k + 3][n]);
        *(ushort4*)(WT + (size_t)(row_off + n0 + n) * ldt + k0 + k) = o;
    }
}

// ---------------- RMSNorm -> bf16 xn ------------------------------------------
__global__ __launch_bounds__(256) void rmsnorm_kernel(const float* __restrict__ x,
                                                      const float* __restrict__ w,
                                                      ushort_t* __restrict__ xnb) {
    int row = blockIdx.x;
    float4 v = ((const float4*)(x + (size_t)row * DIMD))[threadIdx.x];
    float ss = v.x*v.x + v.y*v.y + v.z*v.z + v.w*v.w;
    #pragma unroll
    for (int off = 32; off > 0; off >>= 1) ss += __shfl_xor(ss, off, 64);
    __shared__ float sred[4];
    int wid = threadIdx.x >> 6;
    if ((threadIdx.x & 63) == 0) sred[wid] = ss;
    __syncthreads();
    float tot = sred[0] + sred[1] + sred[2] + sred[3];
    float scale = rsqrtf(tot * (1.0f / DIMD) + EPSR);
    float4 wv = ((const float4*)w)[threadIdx.x];
    ushort4 o;
    o.x = f2bf(v.x * scale * wv.x);
    o.y = f2bf(v.y * scale * wv.y);
    o.z = f2bf(v.z * scale * wv.z);
    o.w = f2bf(v.w * scale * wv.w);
    ((ushort4*)(xnb + (size_t)row * DIMD))[threadIdx.x] = o;
}

// ---------------- bf16 MFMA GEMM: C[M,N] = A[M,K] @ BT[N,K]^T ------------------
// 128x128 tile, BK=64, 4 waves 2x2, 4x4 16x16x32 frags/wave.
// EPI: 5 = GEMM1 split: n<2048 -> fp32 C (xzu, ld 2048); n>=2048 -> bf16 Cb16 (zb)
//      2 = fp32 C = acc + resid
//      4 = fused dt|B|C: n<2048 -> TRANSPOSED bf16 softplus into Cb16[b][n][l];
//          n in [2048,2112) -> Bxo bf16; n in [2112,2176) -> Cxo bf16
template <int EPI>
__global__ __launch_bounds__(256) void mfma_gemm(const ushort_t* __restrict__ A, int lda,
                                                 const ushort_t* __restrict__ BT, int ldb,
                                                 float* __restrict__ C, int ldc,
                                                 ushort_t* __restrict__ Cb16,
                                                 ushort_t* __restrict__ Bxo,
                                                 ushort_t* __restrict__ Cxo,
                                                 const float* __restrict__ bias,
                                                 const float* __restrict__ resid, int ldr,
                                                 int Kdim) {
    __shared__ ushort_t As[128][72];   // +8 pad: row stride 36 dwords -> 2-way (free)
    __shared__ ushort_t Bs[128][72];
    int tid = threadIdx.x;
    int lane = tid & 63, wid = tid >> 6;
    int wr = wid >> 1, wc = wid & 1;
    int m0 = blockIdx.y * 128, n0 = blockIdx.x * 128;

    f32x4 acc[4][4] = {};

    int srow = tid >> 3;              // 0..31 (+32/r)
    int scol = (tid & 7) * 8;         // 0..56

    for (int k0 = 0; k0 < Kdim; k0 += 64) {
        #pragma unroll
        for (int r = 0; r < 4; ++r) {
            int row = r * 32 + srow;
            *(bf16x8*)&As[row][scol] = *(const bf16x8*)(A  + (size_t)(m0 + row) * lda + k0 + scol);
            *(bf16x8*)&Bs[row][scol] = *(const bf16x8*)(BT + (size_t)(n0 + row) * ldb + k0 + scol);
        }
        __syncthreads();
        #pragma unroll
        for (int kk = 0; kk < 64; kk += 32) {
            bf16x8 af[4], bfr[4];
            int fr = lane & 15;
            int fk = kk + (lane >> 4) * 8;
            #pragma unroll
            for (int mi = 0; mi < 4; ++mi)
                af[mi] = *(const bf16x8*)&As[wr * 64 + mi * 16 + fr][fk];
            #pragma unroll
            for (int ni = 0; ni < 4; ++ni)
                bfr[ni] = *(const bf16x8*)&Bs[wc * 64 + ni * 16 + fr][fk];
            #pragma unroll
            for (int mi = 0; mi < 4; ++mi)
                #pragma unroll
                for (int ni = 0; ni < 4; ++ni)
                    acc[mi][ni] = __builtin_amdgcn_mfma_f32_16x16x32_bf16(af[mi], bfr[ni], acc[mi][ni], 0, 0, 0);
        }
        __syncthreads();
    }

    #pragma unroll
    for (int mi = 0; mi < 4; ++mi) {
        int gm = m0 + wr * 64 + mi * 16 + (lane >> 4) * 4;
        #pragma unroll
        for (int ni = 0; ni < 4; ++ni) {
            int gn = n0 + wc * 64 + ni * 16 + (lane & 15);
            f32x4 v = acc[mi][ni];
            if (EPI == 5) {
                #pragma unroll
                for (int r = 0; r < 4; ++r) {
                    if (gn < 2048) C[(size_t)(gm + r) * 2048 + gn] = v[r];
                    else           Cb16[(size_t)(gm + r) * 2048 + (gn - 2048)] = f2bf(v[r]);
                }
            } else if (EPI == 2) {
                #pragma unroll
                for (int r = 0; r < 4; ++r)
                    C[(size_t)(gm + r) * ldc + gn] = v[r] + resid[(size_t)(gm + r) * ldr + gn];
            } else { // EPI == 4
                if (gn < 2048) {
                    int bb = gm >> 10, ll = gm & 1023;   // 4 consecutive m share batch
                    float bsv = bias[gn];
                    ushort4 o;
                    o.x = f2bf(softplus_f(v[0] + bsv));
                    o.y = f2bf(softplus_f(v[1] + bsv));
                    o.z = f2bf(softplus_f(v[2] + bsv));
                    o.w = f2bf(softplus_f(v[3] + bsv));
                    *(ushort4*)(Cb16 + (((size_t)(bb * 2048 + gn)) << 10) + ll) = o;
                } else if (gn < 2112) {
                    #pragma unroll
                    for (int r = 0; r < 4; ++r)
                        Bxo[(size_t)(gm + r) * NSTATE + (gn - 2048)] = f2bf(v[r]);
                } else {
                    #pragma unroll
                    for (int r = 0; r < 4; ++r)
                        Cxo[(size_t)(gm + r) * NSTATE + (gn - 2112)] = f2bf(v[r]);
                }
            }
        }
    }
}

// ---------------- causal dwconv (K=4) + SiLU -> bf16, BOTH layouts -------------
// grid (c-tiles=32, l-tiles=32, b=2), block 256. LDS tile rows l0-3..l0+31.
__global__ __launch_bounds__(256) void conv_silu_kernel(const float* __restrict__ xzu,
                                                        const float* __restrict__ cw,
                                                        const float* __restrict__ cb,
                                                        ushort_t* __restrict__ ubf,
                                                        ushort_t* __restrict__ ut) {
    __shared__ float tile[35][69];
    int tid = threadIdx.x;
    int c0 = blockIdx.x * 64, l0 = blockIdx.y * 32, b = blockIdx.z;
    #pragma unroll
    for (int it = 0; it < 3; ++it) {
        int r = it * 16 + (tid >> 4);
        if (r < 35) {
            int l = l0 - 3 + r;
            int c4 = (tid & 15) * 4;
            float4 v = make_float4(0.f, 0.f, 0.f, 0.f);
            if (l >= 0) v = *(const float4*)(xzu + ((size_t)(b * NL + l)) * INNERD + c0 + c4);
            tile[r][c4 + 0] = v.x; tile[r][c4 + 1] = v.y;
            tile[r][c4 + 2] = v.z; tile[r][c4 + 3] = v.w;
        }
    }
    __syncthreads();
    // phase 2a: transposed out u_t[b][c][l]; thread -> (ci = tid>>2, tq = tid&3)
    {
        int ci = tid >> 2, tq = tid & 3;
        int c = c0 + ci;
        float4 w = *(const float4*)(cw + (size_t)c * 4);
        float bv = cb[c];
        ushort_t o[8];
        #pragma unroll
        for (int j = 0; j < 8; ++j) {
            int jj = tq * 8 + j;
            float a = bv + w.x * tile[jj][ci] + w.y * tile[jj + 1][ci]
                         + w.z * tile[jj + 2][ci] + w.w * tile[jj + 3][ci];
            o[j] = f2bf(silu_f(a));
        }
        size_t base = ((size_t)(b * 2048 + c) << 10) + l0 + tq * 8;
        *(ushort4*)(ut + base)     = make_ushort4(o[0], o[1], o[2], o[3]);
        *(ushort4*)(ut + base + 4) = make_ushort4(o[4], o[5], o[6], o[7]);
    }
    // phase 2b: row-major out u[b*NL+l][c]; thread -> (lj = tid>>3, c8 = (tid&7)*8)
    {
        int lj = tid >> 3, c8 = (tid & 7) * 8;
        ushort_t o[8];
        #pragma unroll
        for (int cc = 0; cc < 8; ++cc) {
            int c = c0 + c8 + cc;
            float4 w = *(const float4*)(cw + (size_t)c * 4);
            float a = cb[c] + w.x * tile[lj][c8 + cc] + w.y * tile[lj + 1][c8 + cc]
                            + w.z * tile[lj + 2][c8 + cc] + w.w * tile[lj + 3][c8 + cc];
            o[cc] = f2bf(silu_f(a));
        }
        size_t base = ((size_t)(b * NL + l0 + lj)) * INNERD + c0 + c8;
        *(ushort4*)(ubf + base)     = make_ushort4(o[0], o[1], o[2], o[3]);
        *(ushort4*)(ubf + base + 4) = make_ushort4(o[4], o[5], o[6], o[7]);
    }
}

// ---------------- selective scan + fused gate ---------------------------------
// one wave per (b,d); lane = state. dt/u broadcast bf16x8 from transposed
// buffers; fold-reduction (10 shfl/group); writes ygb = y*silu(z) bf16.
__global__ __launch_bounds__(256) void scan_kernel(const ushort_t* __restrict__ dtt,
                                                   const ushort_t* __restrict__ ut,
                                                   const ushort_t* __restrict__ bxb,
                                                   const ushort_t* __restrict__ cxb,
                                                   const ushort_t* __restrict__ zb,
                                                   const float* __restrict__ A_log,
                                                   const float* __restrict__ Dp,
                                                   ushort_t* __restrict__ ygb) {
    int lane = threadIdx.x & 63;
    int wid  = threadIdx.x >> 6;
    int g = blockIdx.x * 4 + wid;     // 0..4095
    int b = g >> 11;
    int d = g & 2047;
    float Al   = -__expf(A_log[(size_t)d * NSTATE + lane]);
    float DpdL = (lane == 0) ? Dp[d] : 0.0f;
    float h = 0.0f;
    const ushort_t* dtp = dtt + ((size_t)(b * 2048 + d) << 10);
    const ushort_t* up  = ut  + ((size_t)(b * 2048 + d) << 10);
    const ushort_t* bxp = bxb + (size_t)b * NL * NSTATE + lane;
    const ushort_t* cxp = cxb + (size_t)b * NL * NSTATE + lane;
    // storing-lane mapping: group g=lane>>3 holds sum for t = bitrev3(g)
    int grp = lane >> 3;
    int tg = ((grp & 1) << 2) | (grp & 2) | (grp >> 2);
    const ushort_t* zp = zb  + ((size_t)(b * NL) + tg) * INNERD + d;
    ushort_t*       yp = ygb + ((size_t)(b * NL) + tg) * INNERD + d;
    bool active = (lane & 7) == 0;

    for (int l0 = 0; l0 < NL; l0 += 8) {
        bf16x8 dt8 = *(const bf16x8*)(dtp + l0);   // broadcast 16B
        bf16x8 u8  = *(const bf16x8*)(up  + l0);
        ushort_t bxr[8], cxr[8];
        #pragma unroll
        for (int t = 0; t < 8; ++t) {
            bxr[t] = bxp[(size_t)(l0 + t) * NSTATE];
            cxr[t] = cxp[(size_t)(l0 + t) * NSTATE];
        }
        float p[8];
        #pragma unroll
        for (int t = 0; t < 8; ++t) {
            float dtf = bf2f((ushort_t)dt8[t]);
            float uf  = bf2f((ushort_t)u8[t]);
            float dA = __expf(dtf * Al);
            h = fmaf(dtf * uf, bf2f(bxr[t]), dA * h);
            p[t] = fmaf(DpdL, uf, h * bf2f(cxr[t]));
        }
        // fold 8 values -> 1 (7 shfl), then 3-stage butterfly within 8-lane group
        float q0 = foldpair(p[0], p[1], 32, lane);
        float q1 = foldpair(p[2], p[3], 32, lane);
        float q2 = foldpair(p[4], p[5], 32, lane);
        float q3 = foldpair(p[6], p[7], 32, lane);
        float r0 = foldpair(q0, q1, 16, lane);
        float r1 = foldpair(q2, q3, 16, lane);
        float s  = foldpair(r0, r1, 8, lane);
        s += __shfl_xor(s, 4, 64);
        s += __shfl_xor(s, 2, 64);
        s += __shfl_xor(s, 1, 64);
        if (active) {
            float zf = bf2f(zp[(size_t)l0 * INNERD]);
            float sz = zf / (1.0f + __expf(-zf));
            yp[(size_t)l0 * INNERD] = f2bf(s * sz);
        }
    }
}

extern "C" void kernel_launch(void* const* d_in, const int* in_sizes, int n_in,
                              void* d_out, int out_size, void* d_ws, size_t ws_size,
                              hipStream_t stream) {
    const float* x      = (const float*)d_in[0];
    const float* norm_w = (const float*)d_in[1];
    const float* W_in   = (const float*)d_in[2];
    const float* conv_w = (const float*)d_in[3];
    const float* conv_b = (const float*)d_in[4];
    const float* W_dt   = (const float*)d_in[5];
    const float* b_dt   = (const float*)d_in[6];
    const float* A_log  = (const float*)d_in[7];
    const float* W_B    = (const float*)d_in[8];
    const float* W_C    = (const float*)d_in[9];
    const float* Dp     = (const float*)d_in[10];
    const float* W_out  = (const float*)d_in[11];
    float* out = (float*)d_out;

    // ws layout — 76,546,048 B total (== round-1 proven footprint)
    float*    xzu    = (float*)d_ws;                 // 4,194,304 f32  u-half of xz
    ushort_t* zb     = (ushort_t*)(xzu + 4194304);   // 4,194,304      z-half bf16
    ushort_t* xnb    = zb     + 4194304;             // 2,097,152
    ushort_t* ubf    = xnb    + 2097152;             // 4,194,304  row-major u; reused as ygb
    ushort_t* ut     = ubf    + 4194304;             // 4,194,304  u transposed [b][c][l]
    ushort_t* dtt    = ut     + 4194304;             // 4,194,304  dt transposed [b][n][l]
    ushort_t* bxb    = dtt    + 4194304;             //   131,072
    ushort_t* cxb    = bxb    + 131072;              //   131,072
    ushort_t* BTin   = cxb    + 131072;              // 4,194,304  [4096][1024]
    ushort_t* BTdtbc = BTin   + 4194304;             // 4,456,448  [2176][2048]
    ushort_t* BTout  = BTdtbc + 4456448;             // 2,097,152  [1024][2048]

    // 0. weight convert+transpose to bf16 [N][K]
    transpose_bf16_kernel<<<dim3(64, 16), 256, 0, stream>>>(W_in,  4096, BTin,   1024, 0);
    transpose_bf16_kernel<<<dim3(32, 32), 256, 0, stream>>>(W_dt,  2048, BTdtbc, 2048, 0);
    transpose_bf16_kernel<<<dim3(1,  32), 256, 0, stream>>>(W_B,     64, BTdtbc, 2048, 2048);
    transpose_bf16_kernel<<<dim3(1,  32), 256, 0, stream>>>(W_C,     64, BTdtbc, 2048, 2112);
    transpose_bf16_kernel<<<dim3(16, 32), 256, 0, stream>>>(W_out, 1024, BTout,  2048, 0);

    // 1. RMSNorm -> bf16
    rmsnorm_kernel<<<NT, 256, 0, stream>>>(x, norm_w, xnb);
    // 2. xz = xn @ W_in -> xzu fp32 (n<2048) + zb bf16 (n>=2048)
    mfma_gemm<5><<<dim3(32, 16), 256, 0, stream>>>(xnb, DIMD, BTin, DIMD,
                                                   xzu, 2048, zb, nullptr, nullptr,
                                                   nullptr, nullptr, 0, DIMD);
    // 3. u = silu(dwconv(xzu)) -> ubf row-major + ut transposed
    conv_silu_kernel<<<dim3(32, 32, 2), 256, 0, stream>>>(xzu, conv_w, conv_b, ubf, ut);
    // 4+5. dt = softplus(u@W_dt + b_dt) -> dtt transposed; Bx,Cx = u@[W_B|W_C]
    mfma_gemm<4><<<dim3(17, 16), 256, 0, stream>>>(ubf, INNERD, BTdtbc, INNERD,
                                                   nullptr, 0, dtt, bxb, cxb,
                                                   b_dt, nullptr, 0, INNERD);
    // 6. scan + gate -> ygb (reuses ubf buffer; ubf's GEMM use is done)
    scan_kernel<<<1024, 256, 0, stream>>>(dtt, ut, bxb, cxb, zb, A_log, Dp, ubf);
    // 7. out = yg @ W_out + x
    mfma_gemm<2><<<dim3(8, 16), 256, 0, stream>>>(ubf, INNERD, BTout, INNERD,
                                                  out, DIMD, nullptr, nullptr, nullptr,
                                                  nullptr, x, DIMD, INNERD);
}